// Round 1
// baseline (7054.757 us; speedup 1.0000x reference)
//
#include <hip/hip_runtime.h>
#include <math.h>

// Problem dims (fixed)
#define B_ 64
#define F_ 256
#define T_ 1024
#define H_ 1024
#define O_ 512

typedef short short8 __attribute__((ext_vector_type(8)));   // 8 x bf16 (4 VGPRs)
typedef float f32x4 __attribute__((ext_vector_type(4)));    // MFMA accumulator

__device__ inline float bf2f(unsigned short u) {
    union { unsigned int i; float f; } v; v.i = ((unsigned int)u) << 16; return v.f;
}
__device__ inline unsigned short f2bf(float f) {
    union { float f; unsigned int i; } v; v.f = f;
    unsigned int i = v.i;
    unsigned int r = (i + 0x7fffu + ((i >> 16) & 1u)) >> 16;  // RNE
    return (unsigned short)r;
}

// ---------------------------------------------------------------------------
// Generic fp32 (K x N) -> bf16 (N x K) tile transpose.  src[k][n] -> dst[n][k]
// grid: (N/32, K/32), block: (32, 8)
// ---------------------------------------------------------------------------
__global__ void wt_transpose(const float* __restrict__ src,
                             unsigned short* __restrict__ dst, int K, int N) {
    __shared__ float tile[32][33];
    int n0 = blockIdx.x * 32, k0 = blockIdx.y * 32;
    int tx = threadIdx.x, ty = threadIdx.y;
    for (int i = ty; i < 32; i += 8)
        tile[i][tx] = src[(size_t)(k0 + i) * N + n0 + tx];
    __syncthreads();
    for (int i = ty; i < 32; i += 8)
        dst[(size_t)(n0 + i) * K + k0 + tx] = f2bf(tile[tx][i]);
}

// ---------------------------------------------------------------------------
// x (B,F,T) fp32 -> xT (T,B,F) bf16.  grid: 64*4*16 = 4096 blocks, 256 thr
// ---------------------------------------------------------------------------
__global__ void xpose_x(const float* __restrict__ x, unsigned short* __restrict__ xT) {
    __shared__ float tile[64][65];
    int id = blockIdx.x;
    int b = id >> 6;            // 0..63
    int ft = (id >> 4) & 3;     // 0..3   (F/64)
    int tt = id & 15;           // 0..15  (T/64)
    int f0 = ft * 64, t0 = tt * 64;
    for (int i = threadIdx.x; i < 64 * 64; i += 256) {
        int fl = i >> 6, tl = i & 63;
        tile[fl][tl] = x[((size_t)(b * F_ + f0 + fl)) * T_ + t0 + tl];
    }
    __syncthreads();
    for (int i = threadIdx.x; i < 64 * 64; i += 256) {
        int tl = i >> 6, fl = i & 63;
        xT[((size_t)(t0 + tl) * B_ + b) * F_ + f0 + fl] = f2bf(tile[fl][tl]);
    }
}

// ---------------------------------------------------------------------------
// Input projection: S[r][h] = bf16( xT[r][:] @ Wx[:,h] + b[h] ),  r = t*64+b
// A = xT (65536 x 256 bf16), B = WxT (1024 x 256 bf16, [n][k])
// grid: (16, 1024)  block: 256 (4 waves); block tile 64 rows x 64 cols
// MFMA 16x16x32 layouts (HW-verified):
//   A frag: m = lane&15, k = (lane>>4)*8 + j      (8 contiguous bf16 -> 16B)
//   B frag: n = lane&15, k = (lane>>4)*8 + j
//   C/D   : col = lane&15, row = (lane>>4)*4 + r
// ---------------------------------------------------------------------------
__global__ __launch_bounds__(256) void proj_kernel(
    const unsigned short* __restrict__ xT, const unsigned short* __restrict__ WxT,
    const float* __restrict__ bias, unsigned short* __restrict__ S) {
    int nb = blockIdx.x;   // 0..15
    int mb = blockIdx.y;   // 0..1023
    int wave = threadIdx.x >> 6, lane = threadIdx.x & 63;
    int col16 = lane & 15, quad = lane >> 4;
    int m0 = mb * 64 + wave * 16;
    int n0 = nb * 64;

    f32x4 acc[4];
    for (int s = 0; s < 4; ++s)
        for (int r = 0; r < 4; ++r) acc[s][r] = 0.0f;

    #pragma unroll
    for (int kc = 0; kc < F_ / 32; ++kc) {
        int k0 = kc * 32 + quad * 8;
        short8 a = *reinterpret_cast<const short8*>(xT + (size_t)(m0 + col16) * F_ + k0);
        #pragma unroll
        for (int s = 0; s < 4; ++s) {
            short8 bfr = *reinterpret_cast<const short8*>(
                WxT + (size_t)(n0 + s * 16 + col16) * F_ + k0);
            acc[s] = __builtin_amdgcn_mfma_f32_16x16x32_bf16(a, bfr, acc[s], 0, 0, 0);
        }
    }
    #pragma unroll
    for (int s = 0; s < 4; ++s) {
        int col = n0 + s * 16 + col16;
        float bb = bias[col];
        #pragma unroll
        for (int r = 0; r < 4; ++r) {
            int row = m0 + quad * 4 + r;
            S[(size_t)row * H_ + col] = f2bf(acc[s][r] + bb);
        }
    }
}

// ---------------------------------------------------------------------------
// One recurrence step: St[b][n] = bf16( tanh( xp(St) + Sprev[b][:] @ Wh[:,n] ) )
// St holds xp on entry, h_t on exit (in-place; each 16x16 tile owned by 1 block)
// grid: 256 blocks (4 m-tiles x 64 n-tiles), 64 threads (1 wave)
// ---------------------------------------------------------------------------
__global__ __launch_bounds__(64) void rnn_step(
    const unsigned short* __restrict__ Sprev, unsigned short* __restrict__ St,
    const unsigned short* __restrict__ WhT) {
    int bm = blockIdx.x & 3, bn = blockIdx.x >> 2;
    int lane = threadIdx.x;
    int col16 = lane & 15, quad = lane >> 4;
    int m0 = bm * 16, n0 = bn * 16;

    f32x4 acc;
    #pragma unroll
    for (int r = 0; r < 4; ++r)
        acc[r] = bf2f(St[(size_t)(m0 + quad * 4 + r) * H_ + n0 + col16]);

    if (Sprev) {
        #pragma unroll 8
        for (int kc = 0; kc < H_ / 32; ++kc) {
            int k0 = kc * 32 + quad * 8;
            short8 a = *reinterpret_cast<const short8*>(
                Sprev + (size_t)(m0 + col16) * H_ + k0);
            short8 bfr = *reinterpret_cast<const short8*>(
                WhT + (size_t)(n0 + col16) * H_ + k0);
            acc = __builtin_amdgcn_mfma_f32_16x16x32_bf16(a, bfr, acc, 0, 0, 0);
        }
    }
    #pragma unroll
    for (int r = 0; r < 4; ++r)
        St[(size_t)(m0 + quad * 4 + r) * H_ + n0 + col16] = f2bf(tanhf(acc[r]));
}

// ---------------------------------------------------------------------------
// Output projection: out[b][t][o] = S[t*64+b][:] @ Wout[:,o] + bout[o]
// A = S (65536 x 1024 bf16), B = WoutT (512 x 1024 bf16)
// grid: (8, 1024); block 256 (4 waves); block tile = one t (64 b-rows) x 64 cols
// ---------------------------------------------------------------------------
__global__ __launch_bounds__(256) void out_kernel(
    const unsigned short* __restrict__ S, const unsigned short* __restrict__ WoutT,
    const float* __restrict__ bout, float* __restrict__ out) {
    int nb = blockIdx.x;   // 0..7
    int tt = blockIdx.y;   // 0..1023 (= t)
    int wave = threadIdx.x >> 6, lane = threadIdx.x & 63;
    int col16 = lane & 15, quad = lane >> 4;
    int m0 = tt * 64 + wave * 16;
    int n0 = nb * 64;

    f32x4 acc[4];
    for (int s = 0; s < 4; ++s)
        for (int r = 0; r < 4; ++r) acc[s][r] = 0.0f;

    #pragma unroll 4
    for (int kc = 0; kc < H_ / 32; ++kc) {
        int k0 = kc * 32 + quad * 8;
        short8 a = *reinterpret_cast<const short8*>(S + (size_t)(m0 + col16) * H_ + k0);
        #pragma unroll
        for (int s = 0; s < 4; ++s) {
            short8 bfr = *reinterpret_cast<const short8*>(
                WoutT + (size_t)(n0 + s * 16 + col16) * H_ + k0);
            acc[s] = __builtin_amdgcn_mfma_f32_16x16x32_bf16(a, bfr, acc[s], 0, 0, 0);
        }
    }
    #pragma unroll
    for (int s = 0; s < 4; ++s) {
        int col = n0 + s * 16 + col16;
        float bo = bout[col];
        #pragma unroll
        for (int r = 0; r < 4; ++r) {
            int bidx = wave * 16 + quad * 4 + r;   // batch index within this t
            out[((size_t)bidx * T_ + tt) * O_ + col] = acc[s][r] + bo;
        }
    }
}

// ---------------------------------------------------------------------------
extern "C" void kernel_launch(void* const* d_in, const int* in_sizes, int n_in,
                              void* d_out, int out_size, void* d_ws, size_t ws_size,
                              hipStream_t stream) {
    const float* x    = (const float*)d_in[0];   // (B,F,T)
    const float* Wx   = (const float*)d_in[1];   // (F,H)
    const float* Wh   = (const float*)d_in[2];   // (H,H)
    const float* bias = (const float*)d_in[3];   // (H)
    const float* Wout = (const float*)d_in[4];   // (H,O)
    const float* bout = (const float*)d_in[5];   // (O)
    float* out = (float*)d_out;

    // workspace layout (bf16 = ushort), total ~131.5 MB
    unsigned short* WhT   = (unsigned short*)d_ws;             // H x H   [n][k]
    unsigned short* WxT   = WhT + (size_t)H_ * H_;             // H x F   [n][k]
    unsigned short* WoutT = WxT + (size_t)H_ * F_;             // O x H   [n][k]
    unsigned short* S     = WoutT + (size_t)O_ * H_;           // T x B x H (xp -> states, in place)
    unsigned short* xT    = (unsigned short*)d_out;            // T x B x F scratch (32MB < 128MB out)

    wt_transpose<<<dim3(H_ / 32, H_ / 32), dim3(32, 8), 0, stream>>>(Wh, WhT, H_, H_);
    wt_transpose<<<dim3(H_ / 32, F_ / 32), dim3(32, 8), 0, stream>>>(Wx, WxT, F_, H_);
    wt_transpose<<<dim3(O_ / 32, H_ / 32), dim3(32, 8), 0, stream>>>(Wout, WoutT, H_, O_);
    xpose_x<<<dim3(4096), dim3(256), 0, stream>>>(x, xT);

    proj_kernel<<<dim3(16, 1024), dim3(256), 0, stream>>>(xT, WxT, bias, S);

    for (int t = 0; t < T_; ++t) {
        rnn_step<<<dim3(256), dim3(64), 0, stream>>>(
            t ? S + (size_t)(t - 1) * B_ * H_ : nullptr,
            S + (size_t)t * B_ * H_, WhT);
    }

    out_kernel<<<dim3(8, 1024), dim3(256), 0, stream>>>(S, WoutT, bout, out);
}